// Round 18
// baseline (365.845 us; speedup 1.0000x reference)
//
#include <hip/hip_runtime.h>
#include <stdint.h>

#define NN 50000
#define NE 600000
#define CH 128
#define RT 2                      // row-tiles (of 16 edges) per wave -> 32 edges/wave
#define EPB 128                   // edges per block (4 waves x 32)
#define NPART 196                 // scan partial blocks: ceil(50000/256)

typedef __attribute__((ext_vector_type(8))) short short8;   // 8 bf16
typedef __attribute__((ext_vector_type(4))) float f32x4;
typedef __attribute__((ext_vector_type(4))) uint32_t u32x4;

__device__ __forceinline__ ushort f2bf(float f) {
  union { float f; uint32_t u; } v; v.f = f;
  uint32_t u = v.u;
  return (ushort)((u + 0x7FFFu + ((u >> 16) & 1u)) >> 16);  // RNE, inputs finite
}
__device__ __forceinline__ float bf2f(uint32_t u16) {
  union { uint32_t u; float f; } t; t.u = u16 << 16; return t.f;
}
__device__ __forceinline__ uint32_t cvtpk_bf16(float a, float b) {
  uint32_t r;
  asm("v_cvt_pk_bf16_f32 %0, %1, %2" : "=v"(r) : "v"(a), "v"(b));
  return r;
}

// ---- merged prep: weight fragment pack + x->bf16 + rank histogram ----
// wB layout (ushort): GLOBAL PHASE stream ph=0..27, element (ph*4096 + nt*512 + lane*8 + i)
//   = W[k = ks*32 + (lane>>4)*8 + i][n = nt*16 + (lane&15)]
// phases: 0-11 ew1, 12-15 ew2, 16-23 nw1, 24-27 nw2 (regions contiguous)
__global__ void prep_all_k(const float* __restrict__ ew1, const float* __restrict__ ew2,
                           const float* __restrict__ nw1, const float* __restrict__ nw2,
                           ushort* __restrict__ wB,
                           const float* __restrict__ x, ushort* __restrict__ xb,
                           const int* __restrict__ ei, unsigned* __restrict__ cnt,
                           unsigned* __restrict__ rank) {
  int b = blockIdx.x, tid = threadIdx.x;
  if (b < 448) {                                   // weight fragment pack (114688 elems)
    int idx = b * 256 + tid;
    const float* src; int local;
    if (idx < 49152)      { src = ew1; local = idx; }
    else if (idx < 65536) { src = ew2; local = idx - 49152; }
    else if (idx < 98304) { src = nw1; local = idx - 65536; }
    else                  { src = nw2; local = idx - 98304; }
    int ks   = local >> 12;
    int rem  = local & 4095;
    int nt   = rem >> 9;
    int t    = rem & 511;
    int lane = t >> 3, i = t & 7;
    int k = ks * 32 + (lane >> 4) * 8 + i;
    int n = nt * 16 + (lane & 15);
    wB[idx] = f2bf(src[k * 128 + n]);
  } else if (b < 6698) {                           // x -> bf16 (1.6M float4)
    int i = (b - 448) * 256 + tid;
    const float4 f = reinterpret_cast<const float4*>(x)[i];
    ushort4 r;
    r.x = f2bf(f.x); r.y = f2bf(f.y); r.z = f2bf(f.z); r.w = f2bf(f.w);
    reinterpret_cast<ushort4*>(xb)[i] = r;
  } else {                                         // histogram + per-edge rank
    int e = (b - 6698) * 256 + tid;
    if (e < NE) rank[e] = atomicAdd(&cnt[ei[e]], 1u);
  }
}

// ---- 3-phase parallel exclusive scan of cnt[NN] -> start[NN] ----
__global__ void scan1_k(const unsigned* __restrict__ cnt, unsigned* __restrict__ part) {
  __shared__ unsigned s[256];
  int t = threadIdx.x;
  int i = blockIdx.x * 256 + t;
  s[t] = i < NN ? cnt[i] : 0u;
  __syncthreads();
#pragma unroll
  for (int off = 128; off > 0; off >>= 1) {
    if (t < off) s[t] += s[t + off];
    __syncthreads();
  }
  if (t == 0) part[blockIdx.x] = s[0];
}

__global__ void scan2_k(unsigned* __restrict__ part) {
  __shared__ unsigned s[256];
  int t = threadIdx.x;
  unsigned v = t < NPART ? part[t] : 0u;
  s[t] = v;
  __syncthreads();
#pragma unroll
  for (int off = 1; off < 256; off <<= 1) {
    unsigned u = (t >= off) ? s[t - off] : 0u;
    __syncthreads();
    s[t] += u;
    __syncthreads();
  }
  if (t < NPART) part[t] = s[t] - v;               // exclusive
}

__global__ void scan3_k(const unsigned* __restrict__ cnt, const unsigned* __restrict__ part,
                        unsigned* __restrict__ start) {
  __shared__ unsigned s[256];
  int t = threadIdx.x;
  int i = blockIdx.x * 256 + t;
  unsigned v = i < NN ? cnt[i] : 0u;
  s[t] = v;
  __syncthreads();
#pragma unroll
  for (int off = 1; off < 256; off <<= 1) {
    unsigned u = (t >= off) ? s[t - off] : 0u;
    __syncthreads();
    s[t] += u;
    __syncthreads();
  }
  if (i < NN) start[i] = part[blockIdx.x] + s[t] - v;
}

// XOR-swizzled per-wave h tile (R13-validated): row-major [32][128] ushort,
// stride 256B, byte ^= (row&7)<<4. Bijective per row; 16B granules preserved
// so b128 reads stay intact. Makes the 256 epilogue b16 writes ~2-way (free).
__device__ __forceinline__ ushort* hptr(ushort* hb, int row, int col) {
  return (ushort*)((char*)hb + row * 256 + ((col * 2) ^ ((row & 7) << 4)));
}

// 8 nt-tiles x RT row-tiles of MFMA from one staged LDS phase buffer
__device__ __forceinline__ void mm8(const ushort* Bcbuf, int lane,
                                    const short8 a[RT], f32x4 acc[RT][8]) {
#pragma unroll
  for (int nt = 0; nt < 8; ++nt) {
    short8 b = *reinterpret_cast<const short8*>(Bcbuf + nt * 512 + lane * 8);
#pragma unroll
    for (int rt = 0; rt < RT; ++rt)
      acc[rt][nt] = __builtin_amdgcn_mfma_f32_16x16x32_bf16(a[rt], b, acc[rt][nt], 0, 0, 0);
  }
}

// Fused edge-MLP + node-MLP. Block = 4 waves x 32 edges.  [R12 pipeline]
// 4-deep Bc, loads 4 phases ahead, T4 counted-wait barriers. h XOR-swizzled.
// dest computed inline (start[ei[e]] + rank[e]) — dest_k kernel eliminated.
// LDS = 32K hbuf + 32K Bc = 64 KB -> 2 blocks/CU.
__global__ __launch_bounds__(256, 2) void fused_k(
    const int* __restrict__ ei, const float* __restrict__ edge_attr,
    const ushort* __restrict__ wB,
    const float* __restrict__ eb1, const float* __restrict__ eb2,
    const float* __restrict__ nb1, const float* __restrict__ nb2,
    const ushort* __restrict__ xb, const unsigned* __restrict__ start,
    const unsigned* __restrict__ rank,
    ushort* __restrict__ msg, float* __restrict__ out_e)
{
  __shared__ ushort hbuf[4][RT * 16 * 128];  // 32,768 B (swizzled, no pad)
  __shared__ ushort Bc[4][4096];             // 32,768 B (4-deep phase buffers)
  const int tid  = threadIdx.x;
  const int lane = tid & 63;
  const int widx = tid >> 6;
  const int wbase = blockIdx.x * EPB + widx * (RT * 16);
  const int l15 = lane & 15;
  const int g = lane >> 4;
  const int kg = g * 8;
  ushort* hb = hbuf[widx];

  short8 bt[2][4];   // two staging sets x (2 phases x 16 ushorts)/thread; literal-indexed only

#define LDB2(set, ph) do { \
    const ushort* _s = wB + (size_t)(ph) * 4096 + tid * 16; \
    bt[set][0] = *reinterpret_cast<const short8*>(_s); \
    bt[set][1] = *reinterpret_cast<const short8*>(_s + 8); \
    bt[set][2] = *reinterpret_cast<const short8*>(_s + 4096); \
    bt[set][3] = *reinterpret_cast<const short8*>(_s + 4096 + 8); \
  } while (0)
#define STB2(set, ph) do { \
    ushort* _d0 = &Bc[(ph) & 3][tid * 16]; \
    ushort* _d1 = &Bc[((ph) + 1) & 3][tid * 16]; \
    *reinterpret_cast<short8*>(_d0)     = bt[set][0]; \
    *reinterpret_cast<short8*>(_d0 + 8) = bt[set][1]; \
    *reinterpret_cast<short8*>(_d1)     = bt[set][2]; \
    *reinterpret_cast<short8*>(_d1 + 8) = bt[set][3]; \
  } while (0)
// T4 barrier: LDS-drain only, prefetch loads stay in flight across s_barrier
#define BAR() do { \
    asm volatile("s_waitcnt lgkmcnt(0)" ::: "memory"); \
    __builtin_amdgcn_s_barrier(); \
  } while (0)
#define STEP(s, A0, A1, DO_LDB, DO_STB, DO_BAR) do { \
    __builtin_amdgcn_s_setprio(1); \
    mm8(Bc[(2 * (s)) & 3], lane, A0, acc); \
    mm8(Bc[(2 * (s) + 1) & 3], lane, A1, acc); \
    __builtin_amdgcn_s_setprio(0); \
    if (DO_LDB) LDB2((s) & 1, 2 * (s) + 4); \
    if (DO_STB) STB2(((s) + 1) & 1, 2 * (s) + 2); \
    if (DO_BAR) BAR(); \
  } while (0)
#define LDH(dst, ksl) do { \
    _Pragma("unroll") \
    for (int _rt = 0; _rt < RT; ++_rt) \
      dst[_rt] = *reinterpret_cast<const short8*>(hptr(hb, _rt * 16 + l15, (ksl) * 32 + kg)); \
  } while (0)

  // ---------- prologue: weight pairs 0-1 and 2-3 in flight ----------
  LDB2(0, 0);
  LDB2(1, 2);

  // ---------- all A-side gathers, hoisted ----------
  int rowA[RT], colA[RT], eAc[RT];
#pragma unroll
  for (int rt = 0; rt < RT; ++rt) {
    int e = wbase + rt * 16 + l15;
    eAc[rt] = e < NE ? e : NE - 1;
    rowA[rt] = ei[eAc[rt]];
    colA[rt] = ei[NE + eAc[rt]];
  }
  short8 axr[4][RT], axc[4][RT];       // x[row], x[col] (x[col] reused by GEMM3)
#pragma unroll
  for (int ksl = 0; ksl < 4; ++ksl)
#pragma unroll
    for (int rt = 0; rt < RT; ++rt) {
      axr[ksl][rt] = *reinterpret_cast<const short8*>(xb + rowA[rt] * CH + ksl * 32 + kg);
      axc[ksl][rt] = *reinterpret_cast<const short8*>(xb + colA[rt] * CH + ksl * 32 + kg);
    }
  short8 eab[4][RT];                   // edge_attr, converted to bf16 once
#pragma unroll
  for (int ksl = 0; ksl < 4; ++ksl)
#pragma unroll
    for (int rt = 0; rt < RT; ++rt) {
      const float* pp = edge_attr + (size_t)eAc[rt] * CH + ksl * 32 + kg;
      float4 f0 = *reinterpret_cast<const float4*>(pp);
      float4 f1 = *reinterpret_cast<const float4*>(pp + 4);
      union { u32x4 u; short8 s; } cv;
      cv.u = (u32x4){ cvtpk_bf16(f0.x, f0.y), cvtpk_bf16(f0.z, f0.w),
                      cvtpk_bf16(f1.x, f1.y), cvtpk_bf16(f1.z, f1.w) };
      eab[ksl][rt] = cv.s;
    }
  // inline dest: dp = start[ei[er]] + rank[er]  (dest_k eliminated)
  unsigned dp[RT * 4];
#pragma unroll
  for (int it = 0; it < RT * 4; ++it) {
    int er = wbase + it * 4 + g;
    int erc = er < NE ? er : NE - 1;
    dp[it] = start[ei[erc]] + rank[erc];
  }

  STB2(0, 0);                          // commit pair 0-1 (dep-driven vmcnt wait)
  BAR();                               // pair 0-1 visible; pair 2-3 stays in flight

  const f32x4 zero4 = {0.f, 0.f, 0.f, 0.f};
  f32x4 acc[RT][8];
  short8 ha0[RT], ha1[RT];

  // =========== GEMM1 (steps 0-5): h1 = relu([x[row]|x[col]|ea] @ ew1 + eb1) ===========
#pragma unroll
  for (int rt = 0; rt < RT; ++rt)
#pragma unroll
    for (int nt = 0; nt < 8; ++nt) acc[rt][nt] = zero4;

  STEP(0, axr[0], axr[1], 1, 1, 1);
  STEP(1, axr[2], axr[3], 1, 1, 1);
  STEP(2, axc[0], axc[1], 1, 1, 1);
  STEP(3, axc[2], axc[3], 1, 1, 1);
  STEP(4, eab[0], eab[1], 1, 1, 1);
  STEP(5, eab[2], eab[3], 1, 1, 1);
  // epilogue 1 -> h (C/D layout: row=(l>>4)*4+reg, col=l&15)
#pragma unroll
  for (int nt = 0; nt < 8; ++nt) {
    float bb = eb1[nt * 16 + l15];
#pragma unroll
    for (int rt = 0; rt < RT; ++rt)
#pragma unroll
      for (int r = 0; r < 4; r += 2) {
        float v0 = fmaxf(acc[rt][nt][r] + bb, 0.f);
        float v1 = fmaxf(acc[rt][nt][r + 1] + bb, 0.f);
        uint32_t pk = cvtpk_bf16(v0, v1);
        *hptr(hb, rt * 16 + g * 4 + r,     nt * 16 + l15) = (ushort)(pk & 0xffffu);
        *hptr(hb, rt * 16 + g * 4 + r + 1, nt * 16 + l15) = (ushort)(pk >> 16);
      }
  }

  // =========== GEMM2 (steps 6-7): e_out = h1 @ ew2 + eb2 ===========
#pragma unroll
  for (int rt = 0; rt < RT; ++rt)
#pragma unroll
    for (int nt = 0; nt < 8; ++nt) acc[rt][nt] = zero4;
  LDH(ha0, 0); LDH(ha1, 1);
  STEP(6, ha0, ha1, 1, 1, 1);
  LDH(ha0, 2); LDH(ha1, 3);
  STEP(7, ha0, ha1, 1, 1, 1);
  // epilogue 2: out_e fp32 (exact) + bf16 back to h for GEMM3
#pragma unroll
  for (int nt = 0; nt < 8; ++nt) {
    float bb = eb2[nt * 16 + l15];
#pragma unroll
    for (int rt = 0; rt < RT; ++rt) {
      float v[4];
#pragma unroll
      for (int r = 0; r < 4; ++r) {
        v[r] = acc[rt][nt][r] + bb;
        int erow = wbase + rt * 16 + g * 4 + r;
        if (erow < NE) out_e[(size_t)erow * CH + nt * 16 + l15] = v[r];
      }
#pragma unroll
      for (int r = 0; r < 4; r += 2) {
        uint32_t pk = cvtpk_bf16(v[r], v[r + 1]);
        *hptr(hb, rt * 16 + g * 4 + r,     nt * 16 + l15) = (ushort)(pk & 0xffffu);
        *hptr(hb, rt * 16 + g * 4 + r + 1, nt * 16 + l15) = (ushort)(pk >> 16);
      }
    }
  }

  // =========== GEMM3 (steps 8-11): h2 = relu([x[col]|e_out] @ nw1 + nb1) ===========
#pragma unroll
  for (int rt = 0; rt < RT; ++rt)
#pragma unroll
    for (int nt = 0; nt < 8; ++nt) acc[rt][nt] = zero4;
  STEP(8, axc[0], axc[1], 1, 1, 1);    // x[col] reused from registers
  STEP(9, axc[2], axc[3], 1, 1, 1);
  LDH(ha0, 0); LDH(ha1, 1);
  STEP(10, ha0, ha1, 1, 1, 1);
  LDH(ha0, 2); LDH(ha1, 3);
  STEP(11, ha0, ha1, 1, 1, 1);
  // epilogue 3 -> h
#pragma unroll
  for (int nt = 0; nt < 8; ++nt) {
    float bb = nb1[nt * 16 + l15];
#pragma unroll
    for (int rt = 0; rt < RT; ++rt)
#pragma unroll
      for (int r = 0; r < 4; r += 2) {
        float v0 = fmaxf(acc[rt][nt][r] + bb, 0.f);
        float v1 = fmaxf(acc[rt][nt][r + 1] + bb, 0.f);
        uint32_t pk = cvtpk_bf16(v0, v1);
        *hptr(hb, rt * 16 + g * 4 + r,     nt * 16 + l15) = (ushort)(pk & 0xffffu);
        *hptr(hb, rt * 16 + g * 4 + r + 1, nt * 16 + l15) = (ushort)(pk >> 16);
      }
  }

  // =========== GEMM4 (steps 12-13): msg = h2 @ nw2 + nb2 ===========
#pragma unroll
  for (int rt = 0; rt < RT; ++rt)
#pragma unroll
    for (int nt = 0; nt < 8; ++nt) acc[rt][nt] = zero4;
  LDH(ha0, 0); LDH(ha1, 1);
  STEP(12, ha0, ha1, 0, 1, 1);         // pair 26-27 committed (loaded at step 11)
  LDH(ha0, 2); LDH(ha1, 3);
  STEP(13, ha0, ha1, 0, 0, 0);         // last pair: no prefetch/commit/barrier
#pragma unroll
  for (int nt = 0; nt < 8; ++nt) {
    float bb = nb2[nt * 16 + l15];
#pragma unroll
    for (int rt = 0; rt < RT; ++rt)
#pragma unroll
      for (int r = 0; r < 4; r += 2) {
        uint32_t pk = cvtpk_bf16(acc[rt][nt][r] + bb, acc[rt][nt][r + 1] + bb);
        *hptr(hb, rt * 16 + g * 4 + r,     nt * 16 + l15) = (ushort)(pk & 0xffffu);
        *hptr(hb, rt * 16 + g * 4 + r + 1, nt * 16 + l15) = (ushort)(pk >> 16);
      }
  }
  // msg stores: dwordx4 at inline-computed CSR slot
#pragma unroll
  for (int it = 0; it < RT * 4; ++it) {
    int row = it * 4 + g;
    int er = wbase + row;
    int col = l15 * 8;
    short8 v = *reinterpret_cast<const short8*>(hptr(hb, row, col));
    if (er < NE)
      *reinterpret_cast<short8*>(msg + (size_t)dp[it] * CH + col) = v;
  }
#undef LDB2
#undef STB2
#undef BAR
#undef STEP
#undef LDH
}

// scatter-mean: msg in CSR order -> coalesced streaming read, no atomics.
__global__ __launch_bounds__(256) void reduce_k(const ushort* __restrict__ msg,
    const unsigned* __restrict__ cnt, const unsigned* __restrict__ start,
    float* __restrict__ out_x) {
  int w = blockIdx.x * 4 + (threadIdx.x >> 6);
  if (w >= NN) return;
  int lane = threadIdx.x & 63;
  unsigned deg = cnt[w], s = start[w];
  float a0 = 0.f, a1 = 0.f;
#pragma unroll 4
  for (unsigned j = 0; j < deg; ++j) {
    uint32_t pk = *reinterpret_cast<const uint32_t*>(msg + (size_t)(s + j) * CH + lane * 2);
    a0 += bf2f(pk & 0xffffu);
    a1 += bf2f(pk >> 16);
  }
  float inv = 1.0f / fmaxf((float)deg, 1.0f);
  float2 o; o.x = a0 * inv; o.y = a1 * inv;
  *reinterpret_cast<float2*>(out_x + (size_t)w * CH + lane * 2) = o;
}

extern "C" void kernel_launch(void* const* d_in, const int* in_sizes, int n_in,
                              void* d_out, int out_size, void* d_ws, size_t ws_size,
                              hipStream_t stream) {
  const float* x   = (const float*)d_in[0];
  const int*   ei  = (const int*)d_in[1];
  const float* ea  = (const float*)d_in[2];
  const float* ew1 = (const float*)d_in[3];
  const float* eb1 = (const float*)d_in[4];
  const float* ew2 = (const float*)d_in[5];
  const float* eb2 = (const float*)d_in[6];
  const float* nw1 = (const float*)d_in[7];
  const float* nb1 = (const float*)d_in[8];
  const float* nw2 = (const float*)d_in[9];
  const float* nb2 = (const float*)d_in[10];

  float* out_x = (float*)d_out;                          // [NN][CH]
  float* out_e = (float*)d_out + (size_t)NN * CH;        // [NE][CH]

  // ws layout: msg bf16 [NE][CH] @0 | wB | xb | cnt | start | rank | part
  char* wsb = (char*)d_ws;
  ushort*   msg    = (ushort*)wsb;                                   // 153,600,000 B
  ushort*   wB     = (ushort*)(wsb + 153600000);                     //     229,376 B
  ushort*   xb     = (ushort*)(wsb + 153829376);                     //  12,800,000 B
  unsigned* cnt    = (unsigned*)(wsb + 166629376);                   //     200,000 B
  unsigned* start  = (unsigned*)(wsb + 166829376);                   //     200,000 B
  unsigned* rank   = (unsigned*)(wsb + 167029376);                   //   2,400,000 B
  unsigned* part   = (unsigned*)(wsb + 169429376);                   //         784 B

  hipMemsetAsync(cnt, 0, (size_t)NN * sizeof(unsigned), stream);

  // merged prep: blocks [0,448) weights | [448,6698) x-convert | [6698,9042) rank
  prep_all_k<<<9042, 256, 0, stream>>>(ew1, ew2, nw1, nw2, wB, x, xb, ei, cnt, rank);
  // 3-phase parallel scan
  scan1_k<<<NPART, 256, 0, stream>>>(cnt, part);
  scan2_k<<<1, 256, 0, stream>>>(part);
  scan3_k<<<NPART, 256, 0, stream>>>(cnt, part, start);

  int nblk = (NE + EPB - 1) / EPB;                       // 4688
  fused_k<<<nblk, 256, 0, stream>>>(ei, ea, wB, eb1, eb2, nb1, nb2, xb,
                                    start, rank, msg, out_e);

  reduce_k<<<(NN + 3) / 4, 256, 0, stream>>>(msg, cnt, start, out_x);
}

// Round 19
// 361.321 us; speedup vs baseline: 1.0125x; 1.0125x over previous
//
#include <hip/hip_runtime.h>
#include <stdint.h>

#define NN 50000
#define NE 600000
#define CH 128
#define RT 2                      // row-tiles (of 16 edges) per wave -> 32 edges/wave
#define EPB 128                   // edges per block (4 waves x 32)
#define NPART 196                 // scan partial blocks: ceil(50000/256)

typedef __attribute__((ext_vector_type(8))) short short8;   // 8 bf16
typedef __attribute__((ext_vector_type(4))) float f32x4;
typedef __attribute__((ext_vector_type(4))) uint32_t u32x4;

__device__ __forceinline__ ushort f2bf(float f) {
  union { float f; uint32_t u; } v; v.f = f;
  uint32_t u = v.u;
  return (ushort)((u + 0x7FFFu + ((u >> 16) & 1u)) >> 16);  // RNE, inputs finite
}
__device__ __forceinline__ float bf2f(uint32_t u16) {
  union { uint32_t u; float f; } t; t.u = u16 << 16; return t.f;
}
__device__ __forceinline__ uint32_t cvtpk_bf16(float a, float b) {
  uint32_t r;
  asm("v_cvt_pk_bf16_f32 %0, %1, %2" : "=v"(r) : "v"(a), "v"(b));
  return r;
}

// ---- merged prep: weight fragment pack + x->bf16 + rank histogram ----
// wB layout (ushort): GLOBAL PHASE stream ph=0..27, element (ph*4096 + nt*512 + lane*8 + i)
//   = W[k = ks*32 + (lane>>4)*8 + i][n = nt*16 + (lane&15)]
// phases: 0-11 ew1, 12-15 ew2, 16-23 nw1, 24-27 nw2 (regions contiguous)
__global__ void prep_all_k(const float* __restrict__ ew1, const float* __restrict__ ew2,
                           const float* __restrict__ nw1, const float* __restrict__ nw2,
                           ushort* __restrict__ wB,
                           const float* __restrict__ x, ushort* __restrict__ xb,
                           const int* __restrict__ ei, unsigned* __restrict__ cnt,
                           unsigned* __restrict__ rank) {
  int b = blockIdx.x, tid = threadIdx.x;
  if (b < 448) {                                   // weight fragment pack (114688 elems)
    int idx = b * 256 + tid;
    const float* src; int local;
    if (idx < 49152)      { src = ew1; local = idx; }
    else if (idx < 65536) { src = ew2; local = idx - 49152; }
    else if (idx < 98304) { src = nw1; local = idx - 65536; }
    else                  { src = nw2; local = idx - 98304; }
    int ks   = local >> 12;
    int rem  = local & 4095;
    int nt   = rem >> 9;
    int t    = rem & 511;
    int lane = t >> 3, i = t & 7;
    int k = ks * 32 + (lane >> 4) * 8 + i;
    int n = nt * 16 + (lane & 15);
    wB[idx] = f2bf(src[k * 128 + n]);
  } else if (b < 6698) {                           // x -> bf16 (1.6M float4)
    int i = (b - 448) * 256 + tid;
    const float4 f = reinterpret_cast<const float4*>(x)[i];
    ushort4 r;
    r.x = f2bf(f.x); r.y = f2bf(f.y); r.z = f2bf(f.z); r.w = f2bf(f.w);
    reinterpret_cast<ushort4*>(xb)[i] = r;
  } else {                                         // histogram + per-edge rank
    int e = (b - 6698) * 256 + tid;
    if (e < NE) rank[e] = atomicAdd(&cnt[ei[e]], 1u);
  }
}

// ---- 3-phase parallel exclusive scan of cnt[NN] -> start[NN] ----
__global__ void scan1_k(const unsigned* __restrict__ cnt, unsigned* __restrict__ part) {
  __shared__ unsigned s[256];
  int t = threadIdx.x;
  int i = blockIdx.x * 256 + t;
  s[t] = i < NN ? cnt[i] : 0u;
  __syncthreads();
#pragma unroll
  for (int off = 128; off > 0; off >>= 1) {
    if (t < off) s[t] += s[t + off];
    __syncthreads();
  }
  if (t == 0) part[blockIdx.x] = s[0];
}

__global__ void scan2_k(unsigned* __restrict__ part) {
  __shared__ unsigned s[256];
  int t = threadIdx.x;
  unsigned v = t < NPART ? part[t] : 0u;
  s[t] = v;
  __syncthreads();
#pragma unroll
  for (int off = 1; off < 256; off <<= 1) {
    unsigned u = (t >= off) ? s[t - off] : 0u;
    __syncthreads();
    s[t] += u;
    __syncthreads();
  }
  if (t < NPART) part[t] = s[t] - v;               // exclusive
}

__global__ void scan3_k(const unsigned* __restrict__ cnt, const unsigned* __restrict__ part,
                        unsigned* __restrict__ start) {
  __shared__ unsigned s[256];
  int t = threadIdx.x;
  int i = blockIdx.x * 256 + t;
  unsigned v = i < NN ? cnt[i] : 0u;
  s[t] = v;
  __syncthreads();
#pragma unroll
  for (int off = 1; off < 256; off <<= 1) {
    unsigned u = (t >= off) ? s[t - off] : 0u;
    __syncthreads();
    s[t] += u;
    __syncthreads();
  }
  if (i < NN) start[i] = part[blockIdx.x] + s[t] - v;
}

// dest[e] = start[row] + rank[e]
__global__ void dest_k(const int* __restrict__ ei, const unsigned* __restrict__ start,
                       const unsigned* __restrict__ rank, unsigned* __restrict__ dest) {
  int e = blockIdx.x * 256 + threadIdx.x;
  if (e < NE) dest[e] = start[ei[e]] + rank[e];
}

// 8 nt-tiles x RT row-tiles of MFMA from one staged LDS phase buffer
__device__ __forceinline__ void mm8(const ushort* Bcbuf, int lane,
                                    const short8 a[RT], f32x4 acc[RT][8]) {
#pragma unroll
  for (int nt = 0; nt < 8; ++nt) {
    short8 b = *reinterpret_cast<const short8*>(Bcbuf + nt * 512 + lane * 8);
#pragma unroll
    for (int rt = 0; rt < RT; ++rt)
      acc[rt][nt] = __builtin_amdgcn_mfma_f32_16x16x32_bf16(a[rt], b, acc[rt][nt], 0, 0, 0);
  }
}

// Fused edge-MLP + node-MLP. Block = 4 waves x 32 edges.  [R12 exact]
// Weight stream: 4-deep LDS buffer, loads 4 phases ahead. T4 counted-wait
// barriers: raw s_barrier preceded by lgkmcnt(0) ONLY — prefetch loads stay
// in flight across the barrier. Bc is the only cross-wave LDS; h is per-wave.
// LDS = 34.8 + 32 = 66.8 KB -> 2 blocks/CU.
__global__ __launch_bounds__(256, 2) void fused_k(
    const int* __restrict__ ei, const float* __restrict__ edge_attr,
    const ushort* __restrict__ wB,
    const float* __restrict__ eb1, const float* __restrict__ eb2,
    const float* __restrict__ nb1, const float* __restrict__ nb2,
    const ushort* __restrict__ xb, const unsigned* __restrict__ dest,
    ushort* __restrict__ msg, float* __restrict__ out_e)
{
  __shared__ ushort hbuf[4][RT * 16][136];   // 34,816 B
  __shared__ ushort Bc[4][4096];             // 32,768 B (4-deep phase buffers)
  const int tid  = threadIdx.x;
  const int lane = tid & 63;
  const int widx = tid >> 6;
  const int wbase = blockIdx.x * EPB + widx * (RT * 16);
  const int l15 = lane & 15;
  const int g = lane >> 4;
  const int kg = g * 8;
  ushort (*h)[136] = hbuf[widx];

  short8 bt[2][4];   // two staging sets x (2 phases x 16 ushorts)/thread; literal-indexed only

#define LDB2(set, ph) do { \
    const ushort* _s = wB + (size_t)(ph) * 4096 + tid * 16; \
    bt[set][0] = *reinterpret_cast<const short8*>(_s); \
    bt[set][1] = *reinterpret_cast<const short8*>(_s + 8); \
    bt[set][2] = *reinterpret_cast<const short8*>(_s + 4096); \
    bt[set][3] = *reinterpret_cast<const short8*>(_s + 4096 + 8); \
  } while (0)
#define STB2(set, ph) do { \
    ushort* _d0 = &Bc[(ph) & 3][tid * 16]; \
    ushort* _d1 = &Bc[((ph) + 1) & 3][tid * 16]; \
    *reinterpret_cast<short8*>(_d0)     = bt[set][0]; \
    *reinterpret_cast<short8*>(_d0 + 8) = bt[set][1]; \
    *reinterpret_cast<short8*>(_d1)     = bt[set][2]; \
    *reinterpret_cast<short8*>(_d1 + 8) = bt[set][3]; \
  } while (0)
// T4 barrier: LDS-drain only, prefetch loads stay in flight across s_barrier
#define BAR() do { \
    asm volatile("s_waitcnt lgkmcnt(0)" ::: "memory"); \
    __builtin_amdgcn_s_barrier(); \
  } while (0)
#define STEP(s, A0, A1, DO_LDB, DO_STB, DO_BAR) do { \
    __builtin_amdgcn_s_setprio(1); \
    mm8(Bc[(2 * (s)) & 3], lane, A0, acc); \
    mm8(Bc[(2 * (s) + 1) & 3], lane, A1, acc); \
    __builtin_amdgcn_s_setprio(0); \
    if (DO_LDB) LDB2((s) & 1, 2 * (s) + 4); \
    if (DO_STB) STB2(((s) + 1) & 1, 2 * (s) + 2); \
    if (DO_BAR) BAR(); \
  } while (0)
#define LDH(dst, ksl) do { \
    _Pragma("unroll") \
    for (int _rt = 0; _rt < RT; ++_rt) \
      dst[_rt] = *reinterpret_cast<const short8*>(&h[_rt * 16 + l15][(ksl) * 32 + kg]); \
  } while (0)

  // ---------- prologue: weight pairs 0-1 and 2-3 in flight ----------
  LDB2(0, 0);
  LDB2(1, 2);

  // ---------- all A-side gathers, hoisted ----------
  int rowA[RT], colA[RT], eAc[RT];
#pragma unroll
  for (int rt = 0; rt < RT; ++rt) {
    int e = wbase + rt * 16 + l15;
    eAc[rt] = e < NE ? e : NE - 1;
    rowA[rt] = ei[eAc[rt]];
    colA[rt] = ei[NE + eAc[rt]];
  }
  short8 axr[4][RT], axc[4][RT];       // x[row], x[col] (x[col] reused by GEMM3)
#pragma unroll
  for (int ksl = 0; ksl < 4; ++ksl)
#pragma unroll
    for (int rt = 0; rt < RT; ++rt) {
      axr[ksl][rt] = *reinterpret_cast<const short8*>(xb + rowA[rt] * CH + ksl * 32 + kg);
      axc[ksl][rt] = *reinterpret_cast<const short8*>(xb + colA[rt] * CH + ksl * 32 + kg);
    }
  short8 eab[4][RT];                   // edge_attr, converted to bf16 once
#pragma unroll
  for (int ksl = 0; ksl < 4; ++ksl)
#pragma unroll
    for (int rt = 0; rt < RT; ++rt) {
      const float* pp = edge_attr + (size_t)eAc[rt] * CH + ksl * 32 + kg;
      float4 f0 = *reinterpret_cast<const float4*>(pp);
      float4 f1 = *reinterpret_cast<const float4*>(pp + 4);
      union { u32x4 u; short8 s; } cv;
      cv.u = (u32x4){ cvtpk_bf16(f0.x, f0.y), cvtpk_bf16(f0.z, f0.w),
                      cvtpk_bf16(f1.x, f1.y), cvtpk_bf16(f1.z, f1.w) };
      eab[ksl][rt] = cv.s;
    }
  unsigned dp[RT * 4];                 // CSR slots for msg stores
#pragma unroll
  for (int it = 0; it < RT * 4; ++it) {
    int er = wbase + it * 4 + g;
    dp[it] = dest[er < NE ? er : NE - 1];
  }

  STB2(0, 0);                          // commit pair 0-1 (dep-driven vmcnt wait)
  BAR();                               // pair 0-1 visible; pair 2-3 stays in flight

  const f32x4 zero4 = {0.f, 0.f, 0.f, 0.f};
  f32x4 acc[RT][8];
  short8 ha0[RT], ha1[RT];

  // =========== GEMM1 (steps 0-5): h1 = relu([x[row]|x[col]|ea] @ ew1 + eb1) ===========
#pragma unroll
  for (int rt = 0; rt < RT; ++rt)
#pragma unroll
    for (int nt = 0; nt < 8; ++nt) acc[rt][nt] = zero4;

  STEP(0, axr[0], axr[1], 1, 1, 1);
  STEP(1, axr[2], axr[3], 1, 1, 1);
  STEP(2, axc[0], axc[1], 1, 1, 1);
  STEP(3, axc[2], axc[3], 1, 1, 1);
  STEP(4, eab[0], eab[1], 1, 1, 1);
  STEP(5, eab[2], eab[3], 1, 1, 1);
  // epilogue 1 -> h (C/D layout: row=(l>>4)*4+reg, col=l&15)
#pragma unroll
  for (int nt = 0; nt < 8; ++nt) {
    float bb = eb1[nt * 16 + l15];
#pragma unroll
    for (int rt = 0; rt < RT; ++rt)
#pragma unroll
      for (int r = 0; r < 4; r += 2) {
        float v0 = fmaxf(acc[rt][nt][r] + bb, 0.f);
        float v1 = fmaxf(acc[rt][nt][r + 1] + bb, 0.f);
        uint32_t pk = cvtpk_bf16(v0, v1);
        h[rt * 16 + g * 4 + r][nt * 16 + l15]     = (ushort)(pk & 0xffffu);
        h[rt * 16 + g * 4 + r + 1][nt * 16 + l15] = (ushort)(pk >> 16);
      }
  }

  // =========== GEMM2 (steps 6-7): e_out = h1 @ ew2 + eb2 ===========
#pragma unroll
  for (int rt = 0; rt < RT; ++rt)
#pragma unroll
    for (int nt = 0; nt < 8; ++nt) acc[rt][nt] = zero4;
  LDH(ha0, 0); LDH(ha1, 1);
  STEP(6, ha0, ha1, 1, 1, 1);
  LDH(ha0, 2); LDH(ha1, 3);
  STEP(7, ha0, ha1, 1, 1, 1);
  // epilogue 2: out_e fp32 (exact) + bf16 back to h for GEMM3
#pragma unroll
  for (int nt = 0; nt < 8; ++nt) {
    float bb = eb2[nt * 16 + l15];
#pragma unroll
    for (int rt = 0; rt < RT; ++rt) {
      float v[4];
#pragma unroll
      for (int r = 0; r < 4; ++r) {
        v[r] = acc[rt][nt][r] + bb;
        int erow = wbase + rt * 16 + g * 4 + r;
        if (erow < NE) out_e[(size_t)erow * CH + nt * 16 + l15] = v[r];
      }
#pragma unroll
      for (int r = 0; r < 4; r += 2) {
        uint32_t pk = cvtpk_bf16(v[r], v[r + 1]);
        h[rt * 16 + g * 4 + r][nt * 16 + l15]     = (ushort)(pk & 0xffffu);
        h[rt * 16 + g * 4 + r + 1][nt * 16 + l15] = (ushort)(pk >> 16);
      }
    }
  }

  // =========== GEMM3 (steps 8-11): h2 = relu([x[col]|e_out] @ nw1 + nb1) ===========
#pragma unroll
  for (int rt = 0; rt < RT; ++rt)
#pragma unroll
    for (int nt = 0; nt < 8; ++nt) acc[rt][nt] = zero4;
  STEP(8, axc[0], axc[1], 1, 1, 1);    // x[col] reused from registers
  STEP(9, axc[2], axc[3], 1, 1, 1);
  LDH(ha0, 0); LDH(ha1, 1);
  STEP(10, ha0, ha1, 1, 1, 1);
  LDH(ha0, 2); LDH(ha1, 3);
  STEP(11, ha0, ha1, 1, 1, 1);
  // epilogue 3 -> h
#pragma unroll
  for (int nt = 0; nt < 8; ++nt) {
    float bb = nb1[nt * 16 + l15];
#pragma unroll
    for (int rt = 0; rt < RT; ++rt)
#pragma unroll
      for (int r = 0; r < 4; r += 2) {
        float v0 = fmaxf(acc[rt][nt][r] + bb, 0.f);
        float v1 = fmaxf(acc[rt][nt][r + 1] + bb, 0.f);
        uint32_t pk = cvtpk_bf16(v0, v1);
        h[rt * 16 + g * 4 + r][nt * 16 + l15]     = (ushort)(pk & 0xffffu);
        h[rt * 16 + g * 4 + r + 1][nt * 16 + l15] = (ushort)(pk >> 16);
      }
  }

  // =========== GEMM4 (steps 12-13): msg = h2 @ nw2 + nb2 ===========
#pragma unroll
  for (int rt = 0; rt < RT; ++rt)
#pragma unroll
    for (int nt = 0; nt < 8; ++nt) acc[rt][nt] = zero4;
  LDH(ha0, 0); LDH(ha1, 1);
  STEP(12, ha0, ha1, 0, 1, 1);         // pair 26-27 committed (loaded at step 11)
  LDH(ha0, 2); LDH(ha1, 3);
  STEP(13, ha0, ha1, 0, 0, 0);         // last pair: no prefetch/commit/barrier
#pragma unroll
  for (int nt = 0; nt < 8; ++nt) {
    float bb = nb2[nt * 16 + l15];
#pragma unroll
    for (int rt = 0; rt < RT; ++rt)
#pragma unroll
      for (int r = 0; r < 4; r += 2) {
        uint32_t pk = cvtpk_bf16(acc[rt][nt][r] + bb, acc[rt][nt][r + 1] + bb);
        h[rt * 16 + g * 4 + r][nt * 16 + l15]     = (ushort)(pk & 0xffffu);
        h[rt * 16 + g * 4 + r + 1][nt * 16 + l15] = (ushort)(pk >> 16);
      }
  }
  // msg stores: dwordx4 at prefetched CSR slot
#pragma unroll
  for (int it = 0; it < RT * 4; ++it) {
    int row = it * 4 + g;
    int er = wbase + row;
    int col = l15 * 8;
    short8 v = *reinterpret_cast<const short8*>(&h[row][col]);
    if (er < NE)
      *reinterpret_cast<short8*>(msg + (size_t)dp[it] * CH + col) = v;
  }
#undef LDB2
#undef STB2
#undef BAR
#undef STEP
#undef LDH
}

// scatter-mean: msg in CSR order -> coalesced streaming read, no atomics.
__global__ __launch_bounds__(256) void reduce_k(const ushort* __restrict__ msg,
    const unsigned* __restrict__ cnt, const unsigned* __restrict__ start,
    float* __restrict__ out_x) {
  int w = blockIdx.x * 4 + (threadIdx.x >> 6);
  if (w >= NN) return;
  int lane = threadIdx.x & 63;
  unsigned deg = cnt[w], s = start[w];
  float a0 = 0.f, a1 = 0.f;
#pragma unroll 4
  for (unsigned j = 0; j < deg; ++j) {
    uint32_t pk = *reinterpret_cast<const uint32_t*>(msg + (size_t)(s + j) * CH + lane * 2);
    a0 += bf2f(pk & 0xffffu);
    a1 += bf2f(pk >> 16);
  }
  float inv = 1.0f / fmaxf((float)deg, 1.0f);
  float2 o; o.x = a0 * inv; o.y = a1 * inv;
  *reinterpret_cast<float2*>(out_x + (size_t)w * CH + lane * 2) = o;
}

extern "C" void kernel_launch(void* const* d_in, const int* in_sizes, int n_in,
                              void* d_out, int out_size, void* d_ws, size_t ws_size,
                              hipStream_t stream) {
  const float* x   = (const float*)d_in[0];
  const int*   ei  = (const int*)d_in[1];
  const float* ea  = (const float*)d_in[2];
  const float* ew1 = (const float*)d_in[3];
  const float* eb1 = (const float*)d_in[4];
  const float* ew2 = (const float*)d_in[5];
  const float* eb2 = (const float*)d_in[6];
  const float* nw1 = (const float*)d_in[7];
  const float* nb1 = (const float*)d_in[8];
  const float* nw2 = (const float*)d_in[9];
  const float* nb2 = (const float*)d_in[10];

  float* out_x = (float*)d_out;                          // [NN][CH]
  float* out_e = (float*)d_out + (size_t)NN * CH;        // [NE][CH]

  // ws layout: msg bf16 [NE][CH] @0 | wB | xb | cnt | start | rank | dest | part
  char* wsb = (char*)d_ws;
  ushort*   msg    = (ushort*)wsb;                                   // 153,600,000 B
  ushort*   wB     = (ushort*)(wsb + 153600000);                     //     229,376 B
  ushort*   xb     = (ushort*)(wsb + 153829376);                     //  12,800,000 B
  unsigned* cnt    = (unsigned*)(wsb + 166629376);                   //     200,000 B
  unsigned* start  = (unsigned*)(wsb + 166829376);                   //     200,000 B
  unsigned* rank   = (unsigned*)(wsb + 167029376);                   //   2,400,000 B
  unsigned* dest   = (unsigned*)(wsb + 169429376);                   //   2,400,000 B
  unsigned* part   = (unsigned*)(wsb + 171829376);                   //         784 B

  hipMemsetAsync(cnt, 0, (size_t)NN * sizeof(unsigned), stream);

  // merged prep: blocks [0,448) weights | [448,6698) x-convert | [6698,9042) rank
  prep_all_k<<<9042, 256, 0, stream>>>(ew1, ew2, nw1, nw2, wB, x, xb, ei, cnt, rank);
  // 3-phase parallel scan (replaces single-block scan_k)
  scan1_k<<<NPART, 256, 0, stream>>>(cnt, part);
  scan2_k<<<1, 256, 0, stream>>>(part);
  scan3_k<<<NPART, 256, 0, stream>>>(cnt, part, start);
  dest_k<<<(NE + 255) / 256, 256, 0, stream>>>(ei, start, rank, dest);

  int nblk = (NE + EPB - 1) / EPB;                       // 4688
  fused_k<<<nblk, 256, 0, stream>>>(ei, ea, wB, eb1, eb2, nb1, nb2, xb, dest, msg, out_e);

  reduce_k<<<(NN + 3) / 4, 256, 0, stream>>>(msg, cnt, start, out_x);
}